// Round 1
// baseline (793.615 us; speedup 1.0000x reference)
//
#include <hip/hip_runtime.h>

#define NODES 100000
#define EDGES 640000
#define DF 128

// ---------------------------------------------------------------- copy (init agg = x)
__global__ void copy_vec4(const float4* __restrict__ src, float4* __restrict__ dst, int n4) {
    int i = blockIdx.x * blockDim.x + threadIdx.x;
    const int stride = gridDim.x * blockDim.x;
    for (; i < n4; i += stride) dst[i] = src[i];
}

// ---------------------------------------------------------------- scatter: agg[dst] += feat[src]
__global__ void scatter_add(const float* __restrict__ feat,
                            const int* __restrict__ srcIdx,
                            const int* __restrict__ dstIdx,
                            float* __restrict__ agg) {
    int i = blockIdx.x * blockDim.x + threadIdx.x;
    const int total = EDGES * DF;           // 81.92M < 2^31
    const int stride = gridDim.x * blockDim.x;
    for (; i < total; i += stride) {
        const int e = i >> 7;               // edge id
        const int f = i & (DF - 1);         // feature id
        const int s = srcIdx[e];
        const int d = dstIdx[e];
        atomicAdd(&agg[(size_t)d * DF + f], feat[(size_t)s * DF + f]);
    }
}

// ---------------------------------------------------------------- fused (A @ W + b), optional relu
// A: [NODES,128] f32 (already contains x + aggregated messages)
// W: [128,128] (stored [in][out], y = a @ W), b: [128]
// block: 256 threads, 32 rows per block. thread = (ct 0..31 = 4-col group, rt 0..7 = 4-row group)
__global__ __launch_bounds__(256) void mlp_kernel(const float* __restrict__ A,
                                                  const float* __restrict__ W,
                                                  const float* __restrict__ bias,
                                                  float* __restrict__ out,
                                                  int relu) {
    __shared__ float wlds[DF * DF];   // 64 KB
    __shared__ float alds[32 * DF];   // 16 KB  -> 80 KB total, 2 blocks/CU
    const int tid = threadIdx.x;
    const int row0 = blockIdx.x * 32;

    // stage W (16384 floats = 4096 float4)
    {
        const float4* Wv = (const float4*)W;
        float4* wv = (float4*)wlds;
        for (int i = tid; i < DF * DF / 4; i += 256) wv[i] = Wv[i];
    }
    // stage A tile (32 rows x 128 = 1024 float4)
    {
        const float4* Av = (const float4*)A;
        float4* av = (float4*)alds;
        const int base = row0 * (DF / 4);
        for (int i = tid; i < 32 * DF / 4; i += 256) av[i] = Av[base + i];
    }
    __syncthreads();

    const int ct = tid & 31;   // col group: cols 4*ct .. 4*ct+3
    const int rt = tid >> 5;   // row group: rows rt*4 .. rt*4+3 (local)

    float4 acc[4];
    #pragma unroll
    for (int r = 0; r < 4; ++r) acc[r] = make_float4(0.f, 0.f, 0.f, 0.f);

    const float4* wv = (const float4*)wlds;
    const float4* av = (const float4*)alds;

    #pragma unroll 8
    for (int k4 = 0; k4 < DF / 4; ++k4) {
        // 4 consecutive k-rows of W, our 4-col slice
        const float4 w0 = wv[(k4 * 4 + 0) * 32 + ct];
        const float4 w1 = wv[(k4 * 4 + 1) * 32 + ct];
        const float4 w2 = wv[(k4 * 4 + 2) * 32 + ct];
        const float4 w3 = wv[(k4 * 4 + 3) * 32 + ct];
        #pragma unroll
        for (int r = 0; r < 4; ++r) {
            const float4 a = av[(rt * 4 + r) * 32 + k4];
            acc[r].x = fmaf(a.x, w0.x, fmaf(a.y, w1.x, fmaf(a.z, w2.x, fmaf(a.w, w3.x, acc[r].x))));
            acc[r].y = fmaf(a.x, w0.y, fmaf(a.y, w1.y, fmaf(a.z, w2.y, fmaf(a.w, w3.y, acc[r].y))));
            acc[r].z = fmaf(a.x, w0.z, fmaf(a.y, w1.z, fmaf(a.z, w2.z, fmaf(a.w, w3.z, acc[r].z))));
            acc[r].w = fmaf(a.x, w0.w, fmaf(a.y, w1.w, fmaf(a.z, w2.w, fmaf(a.w, w3.w, acc[r].w))));
        }
    }

    const float4 bv = ((const float4*)bias)[ct];
    #pragma unroll
    for (int r = 0; r < 4; ++r) {
        float4 v = acc[r];
        v.x += bv.x; v.y += bv.y; v.z += bv.z; v.w += bv.w;
        if (relu) {
            v.x = fmaxf(v.x, 0.f); v.y = fmaxf(v.y, 0.f);
            v.z = fmaxf(v.z, 0.f); v.w = fmaxf(v.w, 0.f);
        }
        ((float4*)out)[(size_t)(row0 + rt * 4 + r) * (DF / 4) + ct] = v;
    }
}

extern "C" void kernel_launch(void* const* d_in, const int* in_sizes, int n_in,
                              void* d_out, int out_size, void* d_ws, size_t ws_size,
                              hipStream_t stream) {
    const float* x  = (const float*)d_in[0];
    const int*   ei = (const int*)d_in[1];
    const float* W1 = (const float*)d_in[2];
    const float* b1 = (const float*)d_in[3];
    const float* W2 = (const float*)d_in[4];
    const float* b2 = (const float*)d_in[5];
    float* out = (float*)d_out;

    float* agg = (float*)d_ws;                       // [NODES*DF]
    float* h   = agg + (size_t)NODES * DF;           // [NODES*DF]

    const int* src = ei;            // edge_index[0]
    const int* dst = ei + EDGES;    // edge_index[1]

    const int n4 = NODES * DF / 4;

    // layer 1: agg = x; agg[dst] += x[src]; h = relu(agg @ W1 + b1)
    copy_vec4<<<2048, 256, 0, stream>>>((const float4*)x, (float4*)agg, n4);
    scatter_add<<<4096, 256, 0, stream>>>(x, src, dst, agg);
    mlp_kernel<<<NODES / 32, 256, 0, stream>>>(agg, W1, b1, h, 1);

    // layer 2: agg = h; agg[dst] += h[src]; out = agg @ W2 + b2
    copy_vec4<<<2048, 256, 0, stream>>>((const float4*)h, (float4*)agg, n4);
    scatter_add<<<4096, 256, 0, stream>>>(h, src, dst, agg);
    mlp_kernel<<<NODES / 32, 256, 0, stream>>>(agg, W2, b2, out, 0);
}

// Round 2
// 414.777 us; speedup vs baseline: 1.9134x; 1.9134x over previous
//
#include <hip/hip_runtime.h>

#define NODES 100000
#define EDGES 640000
#define DF 128
#define SCAN_B 256
#define NBLK ((NODES + SCAN_B - 1) / SCAN_B)   // 391

// ---------------------------------------------------------------- CSR build
__global__ void hist_kernel(const int* __restrict__ dstIdx, int* __restrict__ deg) {
    int e = blockIdx.x * blockDim.x + threadIdx.x;
    if (e < EDGES) atomicAdd(&deg[dstIdx[e]], 1);
}

// per-block exclusive scan of deg -> excl, block totals -> bsums
__global__ __launch_bounds__(SCAN_B) void scan_blocks(const int* __restrict__ deg,
                                                      int* __restrict__ excl,
                                                      int* __restrict__ bsums) {
    __shared__ int tmp[SCAN_B];
    const int i = blockIdx.x * SCAN_B + threadIdx.x;
    const int v = (i < NODES) ? deg[i] : 0;
    tmp[threadIdx.x] = v;
    __syncthreads();
    for (int off = 1; off < SCAN_B; off <<= 1) {
        int t = 0;
        if (threadIdx.x >= off) t = tmp[threadIdx.x - off];
        __syncthreads();
        if (threadIdx.x >= off) tmp[threadIdx.x] += t;
        __syncthreads();
    }
    if (i < NODES) excl[i] = tmp[threadIdx.x] - v;   // exclusive
    if (threadIdx.x == SCAN_B - 1) bsums[blockIdx.x] = tmp[SCAN_B - 1];
}

// single-block exclusive scan of the 391 block sums
__global__ __launch_bounds__(512) void scan_top(int* __restrict__ bsums) {
    __shared__ int tmp[512];
    const int i = threadIdx.x;
    const int v = (i < NBLK) ? bsums[i] : 0;
    tmp[i] = v;
    __syncthreads();
    for (int off = 1; off < 512; off <<= 1) {
        int t = 0;
        if (i >= off) t = tmp[i - off];
        __syncthreads();
        if (i >= off) tmp[i] += t;
        __syncthreads();
    }
    if (i < NBLK) bsums[i] = tmp[i] - v;   // exclusive
}

// add block offsets; produce offs + cursor; offs[NODES] = EDGES
__global__ __launch_bounds__(SCAN_B) void scan_add(const int* __restrict__ excl,
                                                   const int* __restrict__ bsums,
                                                   int* __restrict__ offs,
                                                   int* __restrict__ cursor) {
    const int i = blockIdx.x * SCAN_B + threadIdx.x;
    if (i < NODES) {
        const int o = excl[i] + bsums[blockIdx.x];
        offs[i] = o;
        cursor[i] = o;
    }
    if (i == 0) offs[NODES] = EDGES;
}

__global__ void fill_kernel(const int* __restrict__ srcIdx,
                            const int* __restrict__ dstIdx,
                            int* __restrict__ cursor,
                            int* __restrict__ sorted_src) {
    int e = blockIdx.x * blockDim.x + threadIdx.x;
    if (e < EDGES) {
        const int d = dstIdx[e];
        const int pos = atomicAdd(&cursor[d], 1);
        sorted_src[pos] = srcIdx[e];
    }
}

// ---------------------------------------------------------------- gather aggregation
// out[i] = x[i] + sum_{j in N(i)} x[j]; half-wave (32 lanes x float4) per node
__global__ __launch_bounds__(256) void gather_agg(const float4* __restrict__ xf4,
                                                  const int* __restrict__ offs,
                                                  const int* __restrict__ ssrc,
                                                  float4* __restrict__ outf4) {
    const int gid = blockIdx.x * 256 + threadIdx.x;
    const int node = gid >> 5;
    const int lane = gid & 31;
    if (node >= NODES) return;
    float4 acc = xf4[(size_t)node * 32 + lane];
    const int beg = offs[node];
    const int end = offs[node + 1];
    for (int j = beg; j < end; ++j) {
        const int s = ssrc[j];
        const float4 v = xf4[(size_t)s * 32 + lane];
        acc.x += v.x; acc.y += v.y; acc.z += v.z; acc.w += v.w;
    }
    outf4[(size_t)node * 32 + lane] = acc;
}

// ---------------------------------------------------------------- fused (A @ W + b), optional relu
// safe in-place (out may alias A): each block stages its own 32 rows in LDS first
__global__ __launch_bounds__(256) void mlp_kernel(const float* __restrict__ A,
                                                  const float* __restrict__ W,
                                                  const float* __restrict__ bias,
                                                  float* __restrict__ out,
                                                  int relu) {
    __shared__ float wlds[DF * DF];   // 64 KB
    __shared__ float alds[32 * DF];   // 16 KB  -> 80 KB, 2 blocks/CU
    const int tid = threadIdx.x;
    const int row0 = blockIdx.x * 32;

    {
        const float4* Wv = (const float4*)W;
        float4* wv = (float4*)wlds;
        for (int i = tid; i < DF * DF / 4; i += 256) wv[i] = Wv[i];
    }
    {
        const float4* Av = (const float4*)A;
        float4* av = (float4*)alds;
        const int base = row0 * (DF / 4);
        for (int i = tid; i < 32 * DF / 4; i += 256) av[i] = Av[base + i];
    }
    __syncthreads();

    const int ct = tid & 31;
    const int rt = tid >> 5;

    float4 acc[4];
    #pragma unroll
    for (int r = 0; r < 4; ++r) acc[r] = make_float4(0.f, 0.f, 0.f, 0.f);

    const float4* wv = (const float4*)wlds;
    const float4* av = (const float4*)alds;

    #pragma unroll 8
    for (int k4 = 0; k4 < DF / 4; ++k4) {
        const float4 w0 = wv[(k4 * 4 + 0) * 32 + ct];
        const float4 w1 = wv[(k4 * 4 + 1) * 32 + ct];
        const float4 w2 = wv[(k4 * 4 + 2) * 32 + ct];
        const float4 w3 = wv[(k4 * 4 + 3) * 32 + ct];
        #pragma unroll
        for (int r = 0; r < 4; ++r) {
            const float4 a = av[(rt * 4 + r) * 32 + k4];
            acc[r].x = fmaf(a.x, w0.x, fmaf(a.y, w1.x, fmaf(a.z, w2.x, fmaf(a.w, w3.x, acc[r].x))));
            acc[r].y = fmaf(a.x, w0.y, fmaf(a.y, w1.y, fmaf(a.z, w2.y, fmaf(a.w, w3.y, acc[r].y))));
            acc[r].z = fmaf(a.x, w0.z, fmaf(a.y, w1.z, fmaf(a.z, w2.z, fmaf(a.w, w3.z, acc[r].z))));
            acc[r].w = fmaf(a.x, w0.w, fmaf(a.y, w1.w, fmaf(a.z, w2.w, fmaf(a.w, w3.w, acc[r].w))));
        }
    }

    const float4 bv = ((const float4*)bias)[ct];
    #pragma unroll
    for (int r = 0; r < 4; ++r) {
        float4 v = acc[r];
        v.x += bv.x; v.y += bv.y; v.z += bv.z; v.w += bv.w;
        if (relu) {
            v.x = fmaxf(v.x, 0.f); v.y = fmaxf(v.y, 0.f);
            v.z = fmaxf(v.z, 0.f); v.w = fmaxf(v.w, 0.f);
        }
        ((float4*)out)[(size_t)(row0 + rt * 4 + r) * (DF / 4) + ct] = v;
    }
}

extern "C" void kernel_launch(void* const* d_in, const int* in_sizes, int n_in,
                              void* d_out, int out_size, void* d_ws, size_t ws_size,
                              hipStream_t stream) {
    const float* x  = (const float*)d_in[0];
    const int*   ei = (const int*)d_in[1];
    const float* W1 = (const float*)d_in[2];
    const float* b1 = (const float*)d_in[3];
    const float* W2 = (const float*)d_in[4];
    const float* b2 = (const float*)d_in[5];
    float* out = (float*)d_out;

    const int* src = ei;
    const int* dst = ei + EDGES;

    // workspace layout
    float* h = (float*)d_ws;                              // NODES*DF floats (51.2 MB)
    int*   iw = (int*)(h + (size_t)NODES * DF);
    int* deg        = iw;                                 // NODES
    int* excl       = deg + NODES;                        // NODES
    int* offs       = excl + NODES;                       // NODES+1
    int* cursor     = offs + NODES + 1;                   // NODES
    int* bsums      = cursor + NODES;                     // NBLK
    int* sorted_src = bsums + NBLK;                       // EDGES

    // ---- CSR build (once per call, used by both layers)
    hipMemsetAsync(deg, 0, NODES * sizeof(int), stream);
    hist_kernel<<<(EDGES + 255) / 256, 256, 0, stream>>>(dst, deg);
    scan_blocks<<<NBLK, SCAN_B, 0, stream>>>(deg, excl, bsums);
    scan_top<<<1, 512, 0, stream>>>(bsums);
    scan_add<<<NBLK, SCAN_B, 0, stream>>>(excl, bsums, offs, cursor);
    fill_kernel<<<(EDGES + 255) / 256, 256, 0, stream>>>(src, dst, cursor, sorted_src);

    const int agg_blocks = (NODES * 32 + 255) / 256;  // 12500

    // ---- layer 1: d_out = x + gather; h = relu(d_out @ W1 + b1)
    gather_agg<<<agg_blocks, 256, 0, stream>>>((const float4*)x, offs, sorted_src, (float4*)out);
    mlp_kernel<<<(NODES + 31) / 32, 256, 0, stream>>>(out, W1, b1, h, 1);

    // ---- layer 2: d_out = h + gather; d_out = d_out @ W2 + b2 (in-place)
    gather_agg<<<agg_blocks, 256, 0, stream>>>((const float4*)h, offs, sorted_src, (float4*)out);
    mlp_kernel<<<(NODES + 31) / 32, 256, 0, stream>>>(out, W2, b2, out, 0);
}

// Round 4
// 189.740 us; speedup vs baseline: 4.1827x; 2.1860x over previous
//
#include <hip/hip_runtime.h>

#define NODES 100000
#define EDGES 640000
#define DF 128
#define SCAN_B 256
#define NBLK ((NODES + SCAN_B - 1) / SCAN_B)   // 391

typedef short bf16x8 __attribute__((ext_vector_type(8)));
typedef float f32x4 __attribute__((ext_vector_type(4)));

__device__ __forceinline__ unsigned short f2bf(float f) {
    unsigned u = __builtin_bit_cast(unsigned, f);
    u += 0x7FFFu + ((u >> 16) & 1u);          // round-to-nearest-even
    return (unsigned short)(u >> 16);
}
__device__ __forceinline__ float bflo(unsigned w) { return __builtin_bit_cast(float, w << 16); }
__device__ __forceinline__ float bfhi(unsigned w) { return __builtin_bit_cast(float, w & 0xFFFF0000u); }

// ---------------------------------------------------------------- CSR build
__global__ void hist_kernel(const int* __restrict__ dstIdx, int* __restrict__ deg) {
    int e = blockIdx.x * blockDim.x + threadIdx.x;
    if (e < EDGES) atomicAdd(&deg[dstIdx[e]], 1);
}

__global__ __launch_bounds__(SCAN_B) void scan_blocks(const int* __restrict__ deg,
                                                      int* __restrict__ excl,
                                                      int* __restrict__ bsums) {
    __shared__ int tmp[SCAN_B];
    const int i = blockIdx.x * SCAN_B + threadIdx.x;
    const int v = (i < NODES) ? deg[i] : 0;
    tmp[threadIdx.x] = v;
    __syncthreads();
    for (int off = 1; off < SCAN_B; off <<= 1) {
        int t = 0;
        if (threadIdx.x >= off) t = tmp[threadIdx.x - off];
        __syncthreads();
        if (threadIdx.x >= off) tmp[threadIdx.x] += t;
        __syncthreads();
    }
    if (i < NODES) excl[i] = tmp[threadIdx.x] - v;
    if (threadIdx.x == SCAN_B - 1) bsums[blockIdx.x] = tmp[SCAN_B - 1];
}

__global__ __launch_bounds__(512) void scan_top(int* __restrict__ bsums) {
    __shared__ int tmp[512];
    const int i = threadIdx.x;
    const int v = (i < NBLK) ? bsums[i] : 0;
    tmp[i] = v;
    __syncthreads();
    for (int off = 1; off < 512; off <<= 1) {
        int t = 0;
        if (i >= off) t = tmp[i - off];
        __syncthreads();
        if (i >= off) tmp[i] += t;
        __syncthreads();
    }
    if (i < NBLK) bsums[i] = tmp[i] - v;
}

__global__ __launch_bounds__(SCAN_B) void scan_add(const int* __restrict__ excl,
                                                   const int* __restrict__ bsums,
                                                   int* __restrict__ offs,
                                                   int* __restrict__ cursor) {
    const int i = blockIdx.x * SCAN_B + threadIdx.x;
    if (i < NODES) {
        const int o = excl[i] + bsums[blockIdx.x];
        offs[i] = o;
        cursor[i] = o;
    }
    if (i == 0) offs[NODES] = EDGES;
}

__global__ void fill_kernel(const int* __restrict__ srcIdx,
                            const int* __restrict__ dstIdx,
                            int* __restrict__ cursor,
                            int* __restrict__ sorted_src) {
    int e = blockIdx.x * blockDim.x + threadIdx.x;
    if (e < EDGES) {
        const int d = dstIdx[e];
        const int pos = atomicAdd(&cursor[d], 1);
        sorted_src[pos] = srcIdx[e];
    }
}

// ---------------------------------------------------------------- f32 -> bf16 convert (8 elems/thread)
__global__ void conv_bf16(const float4* __restrict__ in, uint4* __restrict__ out, int nchunk) {
    int i = blockIdx.x * blockDim.x + threadIdx.x;
    const int stride = gridDim.x * blockDim.x;
    for (; i < nchunk; i += stride) {
        const float4 a = in[i * 2], b = in[i * 2 + 1];
        uint4 o;
        o.x = (unsigned)f2bf(a.x) | ((unsigned)f2bf(a.y) << 16);
        o.y = (unsigned)f2bf(a.z) | ((unsigned)f2bf(a.w) << 16);
        o.z = (unsigned)f2bf(b.x) | ((unsigned)f2bf(b.y) << 16);
        o.w = (unsigned)f2bf(b.z) | ((unsigned)f2bf(b.w) << 16);
        out[i] = o;
    }
}

// ---------------------------------------------------------------- W [k][n] f32 -> Wt [n][k] bf16 (both layers)
__global__ void prep_w(const float* __restrict__ W1, const float* __restrict__ W2,
                       unsigned short* __restrict__ Wt1, unsigned short* __restrict__ Wt2) {
    const int idx = blockIdx.x * blockDim.x + threadIdx.x;   // 0..32767
    const float* src = (idx < 16384) ? W1 : W2;
    unsigned short* dst = (idx < 16384) ? Wt1 : Wt2;
    const int r = idx & 16383;
    const int n = r & 127, k = r >> 7;
    dst[n * 128 + k] = f2bf(src[k * 128 + n]);
}

// ---------------------------------------------------------------- gather: A[i] = x[i] + sum_{j in N(i)} x[j]  (bf16 io, f32 accum)
__global__ __launch_bounds__(256) void gather_bf16(const uint4* __restrict__ xb,
                                                   const int* __restrict__ offs,
                                                   const int* __restrict__ ssrc,
                                                   uint4* __restrict__ ab) {
    const int gid = blockIdx.x * 256 + threadIdx.x;
    const int node = gid >> 4;         // 16 lanes per node, 16B (8 bf16) per lane
    const int lane = gid & 15;
    if (node >= NODES) return;

    float a[8];
    {
        const uint4 u = xb[(size_t)node * 16 + lane];
        a[0] = bflo(u.x); a[1] = bfhi(u.x);
        a[2] = bflo(u.y); a[3] = bfhi(u.y);
        a[4] = bflo(u.z); a[5] = bfhi(u.z);
        a[6] = bflo(u.w); a[7] = bfhi(u.w);
    }
    const int beg = offs[node];
    const int end = offs[node + 1];
    for (int j = beg; j < end; ++j) {
        const uint4 v = xb[(size_t)ssrc[j] * 16 + lane];
        a[0] += bflo(v.x); a[1] += bfhi(v.x);
        a[2] += bflo(v.y); a[3] += bfhi(v.y);
        a[4] += bflo(v.z); a[5] += bfhi(v.z);
        a[6] += bflo(v.w); a[7] += bfhi(v.w);
    }
    uint4 o;
    o.x = (unsigned)f2bf(a[0]) | ((unsigned)f2bf(a[1]) << 16);
    o.y = (unsigned)f2bf(a[2]) | ((unsigned)f2bf(a[3]) << 16);
    o.z = (unsigned)f2bf(a[4]) | ((unsigned)f2bf(a[5]) << 16);
    o.w = (unsigned)f2bf(a[6]) | ((unsigned)f2bf(a[7]) << 16);
    ab[(size_t)node * 16 + lane] = o;
}

// ---------------------------------------------------------------- MFMA MLP: out = A @ Wt^T + b  (A bf16 [M,128], Wt bf16 [n][k])
// block: 256 thr = 4 waves; 64 rows/block (16 rows/wave); N=128 = 8 tiles; K=128 = 4 steps of 32.
template <int RELU, int OUT_BF16>
__global__ __launch_bounds__(256) void mlp_mfma(const unsigned short* __restrict__ A,
                                                const uint4* __restrict__ Wt4,
                                                const float* __restrict__ bias,
                                                void* __restrict__ outp) {
    __shared__ __align__(16) unsigned char wlds[32768];                    // swizzled Wt
    __shared__ __align__(16) unsigned char epi[OUT_BF16 ? 16384 : 16];     // per-wave transpose buffer

    const int tid = threadIdx.x;
    // stage Wt -> LDS with XOR swizzle (byte ^= (row&7)<<4), reg-staged so both sides swizzle
    #pragma unroll
    for (int i = 0; i < 8; ++i) {
        const int c = i * 256 + tid;            // 16B chunk index; row R = c>>4
        const uint4 v = Wt4[c];
        const int byte = (c * 16) ^ (((c >> 4) & 7) << 4);
        *(uint4*)(wlds + byte) = v;
    }

    const int wv = tid >> 6;          // wave 0..3
    const int l  = tid & 63;
    const int lr = l & 15;            // A-row / B-col within tile
    const int g  = l >> 4;            // k-group
    const int row0 = blockIdx.x * 64 + wv * 16;

    // A fragments straight from global (row-major, contiguous in k)
    int arow = row0 + lr;
    if (arow >= NODES) arow = 0;      // clamp (stores are guarded)
    const unsigned short* Ar = A + (size_t)arow * DF + g * 8;
    bf16x8 af[4];
    #pragma unroll
    for (int t = 0; t < 4; ++t) af[t] = *(const bf16x8*)(Ar + t * 32);

    float bv[8];
    #pragma unroll
    for (int nt = 0; nt < 8; ++nt) bv[nt] = bias[nt * 16 + lr];

    f32x4 acc[8];
    #pragma unroll
    for (int nt = 0; nt < 8; ++nt) acc[nt] = (f32x4)(0.f);

    __syncthreads();

    #pragma unroll
    for (int t = 0; t < 4; ++t) {
        #pragma unroll
        for (int nt = 0; nt < 8; ++nt) {
            const int byte = ((nt * 16 + lr) * 256 + ((((t * 4 + g) * 16) ^ ((l & 7) << 4))));
            const bf16x8 bf = *(const bf16x8*)(wlds + byte);
            acc[nt] = __builtin_amdgcn_mfma_f32_16x16x32_bf16(af[t], bf, acc[nt], 0, 0, 0);
        }
    }

    if constexpr (OUT_BF16) {
        // transpose through per-wave LDS for coalesced bf16 row stores
        unsigned char* my = epi + wv * 4096;
        #pragma unroll
        for (int nt = 0; nt < 8; ++nt) {
            #pragma unroll
            for (int r = 0; r < 4; ++r) {
                float v = acc[nt][r] + bv[nt];
                if (RELU) v = fmaxf(v, 0.f);
                const int R = g * 4 + r;                          // row within 16-row tile
                const int byte = (R * 256 + (nt * 16 + lr) * 2) ^ ((R & 7) << 4);
                *(unsigned short*)(my + byte) = f2bf(v);
            }
        }
        __syncthreads();
        unsigned short* outh = (unsigned short*)outp;
        #pragma unroll
        for (int p = 0; p < 4; ++p) {
            const int R = p * 4 + g;
            const uint4 v = *(const uint4*)(my + ((R * 256 + lr * 16) ^ ((R & 7) << 4)));
            const int gr = row0 + R;
            if (gr < NODES) *(uint4*)(outh + (size_t)gr * DF + lr * 8) = v;
        }
    } else {
        float* outf = (float*)outp;
        #pragma unroll
        for (int nt = 0; nt < 8; ++nt) {
            #pragma unroll
            for (int r = 0; r < 4; ++r) {
                const int gr = row0 + g * 4 + r;
                float v = acc[nt][r] + bv[nt];
                if (RELU) v = fmaxf(v, 0.f);
                if (gr < NODES) outf[(size_t)gr * DF + nt * 16 + lr] = v;
            }
        }
    }
}

extern "C" void kernel_launch(void* const* d_in, const int* in_sizes, int n_in,
                              void* d_out, int out_size, void* d_ws, size_t ws_size,
                              hipStream_t stream) {
    const float* x  = (const float*)d_in[0];
    const int*   ei = (const int*)d_in[1];
    const float* W1 = (const float*)d_in[2];
    const float* b1 = (const float*)d_in[3];
    const float* W2 = (const float*)d_in[4];
    const float* b2 = (const float*)d_in[5];
    float* out = (float*)d_out;

    const int* src = ei;
    const int* dst = ei + EDGES;

    // ---- workspace layout (16B-aligned chunks)
    unsigned short* xb   = (unsigned short*)d_ws;                 // NODES*DF bf16 (25.6 MB)
    unsigned short* abuf = xb + (size_t)NODES * DF;               // NODES*DF bf16
    unsigned short* hb   = abuf + (size_t)NODES * DF;             // NODES*DF bf16
    unsigned short* Wt1  = hb + (size_t)NODES * DF;               // 16384
    unsigned short* Wt2  = Wt1 + 16384;                           // 16384
    int* iw = (int*)(Wt2 + 16384);
    int* deg        = iw;
    int* excl       = deg + NODES;
    int* offs       = excl + NODES;
    int* cursor     = offs + NODES + 1;
    int* bsums      = cursor + NODES;
    int* sorted_src = bsums + NBLK + 1;

    // ---- CSR build
    hipMemsetAsync(deg, 0, NODES * sizeof(int), stream);
    hist_kernel<<<(EDGES + 255) / 256, 256, 0, stream>>>(dst, deg);
    scan_blocks<<<NBLK, SCAN_B, 0, stream>>>(deg, excl, bsums);
    scan_top<<<1, 512, 0, stream>>>(bsums);
    scan_add<<<NBLK, SCAN_B, 0, stream>>>(excl, bsums, offs, cursor);
    fill_kernel<<<(EDGES + 255) / 256, 256, 0, stream>>>(src, dst, cursor, sorted_src);

    // ---- precompute bf16 views
    conv_bf16<<<2048, 256, 0, stream>>>((const float4*)x, (uint4*)xb, NODES * DF / 8);
    prep_w<<<128, 256, 0, stream>>>(W1, W2, Wt1, Wt2);

    const int gblocks = (NODES * 16 + 255) / 256;   // 6250
    const int mblocks = (NODES + 63) / 64;          // 1563

    // ---- layer 1
    gather_bf16<<<gblocks, 256, 0, stream>>>((const uint4*)xb, offs, sorted_src, (uint4*)abuf);
    mlp_mfma<1, 1><<<mblocks, 256, 0, stream>>>(abuf, (const uint4*)Wt1, b1, hb);

    // ---- layer 2
    gather_bf16<<<gblocks, 256, 0, stream>>>((const uint4*)hb, offs, sorted_src, (uint4*)abuf);
    mlp_mfma<0, 0><<<mblocks, 256, 0, stream>>>(abuf, (const uint4*)Wt2, b2, out);
}

// Round 6
// 178.824 us; speedup vs baseline: 4.4380x; 1.0610x over previous
//
#include <hip/hip_runtime.h>

#define NODES 100000
#define EDGES 640000
#define DF 128
#define SCAN_B 256
#define NBLK ((NODES + SCAN_B - 1) / SCAN_B)   // 391

typedef short bf16x8 __attribute__((ext_vector_type(8)));
typedef float f32x4 __attribute__((ext_vector_type(4)));

__device__ __forceinline__ unsigned short f2bf(float f) {
    unsigned u = __builtin_bit_cast(unsigned, f);
    u += 0x7FFFu + ((u >> 16) & 1u);          // round-to-nearest-even
    return (unsigned short)(u >> 16);
}
__device__ __forceinline__ float bflo(unsigned w) { return __builtin_bit_cast(float, w << 16); }
__device__ __forceinline__ float bfhi(unsigned w) { return __builtin_bit_cast(float, w & 0xFFFF0000u); }

// ---------------------------------------------------------------- CSR build
__global__ void hist_kernel(const int* __restrict__ dstIdx, int* __restrict__ deg) {
    int e = blockIdx.x * blockDim.x + threadIdx.x;
    if (e < EDGES) atomicAdd(&deg[dstIdx[e]], 1);
}

__global__ __launch_bounds__(SCAN_B) void scan_blocks(const int* __restrict__ deg,
                                                      int* __restrict__ excl,
                                                      int* __restrict__ bsums) {
    __shared__ int tmp[SCAN_B];
    const int i = blockIdx.x * SCAN_B + threadIdx.x;
    const int v = (i < NODES) ? deg[i] : 0;
    tmp[threadIdx.x] = v;
    __syncthreads();
    for (int off = 1; off < SCAN_B; off <<= 1) {
        int t = 0;
        if (threadIdx.x >= off) t = tmp[threadIdx.x - off];
        __syncthreads();
        if (threadIdx.x >= off) tmp[threadIdx.x] += t;
        __syncthreads();
    }
    if (i < NODES) excl[i] = tmp[threadIdx.x] - v;
    if (threadIdx.x == SCAN_B - 1) bsums[blockIdx.x] = tmp[SCAN_B - 1];
}

__global__ __launch_bounds__(512) void scan_top(int* __restrict__ bsums) {
    __shared__ int tmp[512];
    const int i = threadIdx.x;
    const int v = (i < NBLK) ? bsums[i] : 0;
    tmp[i] = v;
    __syncthreads();
    for (int off = 1; off < 512; off <<= 1) {
        int t = 0;
        if (i >= off) t = tmp[i - off];
        __syncthreads();
        if (i >= off) tmp[i] += t;
        __syncthreads();
    }
    if (i < NBLK) bsums[i] = tmp[i] - v;
}

__global__ __launch_bounds__(SCAN_B) void scan_add(const int* __restrict__ excl,
                                                   const int* __restrict__ bsums,
                                                   int* __restrict__ offs,
                                                   int* __restrict__ cursor) {
    const int i = blockIdx.x * SCAN_B + threadIdx.x;
    if (i < NODES) {
        const int o = excl[i] + bsums[blockIdx.x];
        offs[i] = o;
        cursor[i] = o;
    }
    if (i == 0) offs[NODES] = EDGES;
}

__global__ void fill_kernel(const int* __restrict__ srcIdx,
                            const int* __restrict__ dstIdx,
                            int* __restrict__ cursor,
                            int* __restrict__ sorted_src) {
    int e = blockIdx.x * blockDim.x + threadIdx.x;
    if (e < EDGES) {
        const int d = dstIdx[e];
        const int pos = atomicAdd(&cursor[d], 1);
        sorted_src[pos] = srcIdx[e];
    }
}

// ---------------------------------------------------------------- f32 -> bf16 convert (8 elems/thread)
__global__ void conv_bf16(const float4* __restrict__ in, uint4* __restrict__ out, int nchunk) {
    int i = blockIdx.x * blockDim.x + threadIdx.x;
    const int stride = gridDim.x * blockDim.x;
    for (; i < nchunk; i += stride) {
        const float4 a = in[i * 2], b = in[i * 2 + 1];
        uint4 o;
        o.x = (unsigned)f2bf(a.x) | ((unsigned)f2bf(a.y) << 16);
        o.y = (unsigned)f2bf(a.z) | ((unsigned)f2bf(a.w) << 16);
        o.z = (unsigned)f2bf(b.x) | ((unsigned)f2bf(b.y) << 16);
        o.w = (unsigned)f2bf(b.z) | ((unsigned)f2bf(b.w) << 16);
        out[i] = o;
    }
}

// ---------------------------------------------------------------- W [k][n] f32 -> Wt [n][k] bf16 (both layers)
__global__ void prep_w(const float* __restrict__ W1, const float* __restrict__ W2,
                       unsigned short* __restrict__ Wt1, unsigned short* __restrict__ Wt2) {
    const int idx = blockIdx.x * blockDim.x + threadIdx.x;   // 0..32767
    const float* src = (idx < 16384) ? W1 : W2;
    unsigned short* dst = (idx < 16384) ? Wt1 : Wt2;
    const int r = idx & 16383;
    const int n = r & 127, k = r >> 7;
    dst[n * 128 + k] = f2bf(src[k * 128 + n]);
}

// ---------------------------------------------------------------- gather: A[i] = x[i] + sum_{j in N(i)} x[j]
// 16 lanes/node, 16B/lane; 4-way edge unroll for memory-level parallelism
__global__ __launch_bounds__(256) void gather_bf16(const uint4* __restrict__ xb,
                                                   const int* __restrict__ offs,
                                                   const int* __restrict__ ssrc,
                                                   uint4* __restrict__ ab) {
    const int gid = blockIdx.x * 256 + threadIdx.x;
    const int node = gid >> 4;
    const int lane = gid & 15;
    if (node >= NODES) return;

    float a[8];
    {
        const uint4 u = xb[(size_t)node * 16 + lane];
        a[0] = bflo(u.x); a[1] = bfhi(u.x);
        a[2] = bflo(u.y); a[3] = bfhi(u.y);
        a[4] = bflo(u.z); a[5] = bfhi(u.z);
        a[6] = bflo(u.w); a[7] = bfhi(u.w);
    }
    const int beg = offs[node];
    const int end = offs[node + 1];
    int j = beg;
    // main: 4 independent row loads in flight per iteration
    for (; j + 4 <= end; j += 4) {
        const int s0 = ssrc[j + 0];
        const int s1 = ssrc[j + 1];
        const int s2 = ssrc[j + 2];
        const int s3 = ssrc[j + 3];
        const uint4 v0 = xb[(size_t)s0 * 16 + lane];
        const uint4 v1 = xb[(size_t)s1 * 16 + lane];
        const uint4 v2 = xb[(size_t)s2 * 16 + lane];
        const uint4 v3 = xb[(size_t)s3 * 16 + lane];
        a[0] += bflo(v0.x); a[1] += bfhi(v0.x); a[2] += bflo(v0.y); a[3] += bfhi(v0.y);
        a[4] += bflo(v0.z); a[5] += bfhi(v0.z); a[6] += bflo(v0.w); a[7] += bfhi(v0.w);
        a[0] += bflo(v1.x); a[1] += bfhi(v1.x); a[2] += bflo(v1.y); a[3] += bfhi(v1.y);
        a[4] += bflo(v1.z); a[5] += bfhi(v1.z); a[6] += bflo(v1.w); a[7] += bfhi(v1.w);
        a[0] += bflo(v2.x); a[1] += bfhi(v2.x); a[2] += bflo(v2.y); a[3] += bfhi(v2.y);
        a[4] += bflo(v2.z); a[5] += bfhi(v2.z); a[6] += bflo(v2.w); a[7] += bfhi(v2.w);
        a[0] += bflo(v3.x); a[1] += bfhi(v3.x); a[2] += bflo(v3.y); a[3] += bfhi(v3.y);
        a[4] += bflo(v3.z); a[5] += bfhi(v3.z); a[6] += bflo(v3.w); a[7] += bfhi(v3.w);
    }
    // tail (<=3)
    for (; j < end; ++j) {
        const uint4 v = xb[(size_t)ssrc[j] * 16 + lane];
        a[0] += bflo(v.x); a[1] += bfhi(v.x); a[2] += bflo(v.y); a[3] += bfhi(v.y);
        a[4] += bflo(v.z); a[5] += bfhi(v.z); a[6] += bflo(v.w); a[7] += bfhi(v.w);
    }
    uint4 o;
    o.x = (unsigned)f2bf(a[0]) | ((unsigned)f2bf(a[1]) << 16);
    o.y = (unsigned)f2bf(a[2]) | ((unsigned)f2bf(a[3]) << 16);
    o.z = (unsigned)f2bf(a[4]) | ((unsigned)f2bf(a[5]) << 16);
    o.w = (unsigned)f2bf(a[6]) | ((unsigned)f2bf(a[7]) << 16);
    ab[(size_t)node * 16 + lane] = o;
}

// ---------------------------------------------------------------- MFMA MLP: out = A @ Wt^T + b
template <int RELU, int OUT_BF16>
__global__ __launch_bounds__(256) void mlp_mfma(const unsigned short* __restrict__ A,
                                                const uint4* __restrict__ Wt4,
                                                const float* __restrict__ bias,
                                                void* __restrict__ outp) {
    __shared__ __align__(16) unsigned char wlds[32768];
    __shared__ __align__(16) unsigned char epi[OUT_BF16 ? 16384 : 16];

    const int tid = threadIdx.x;
    #pragma unroll
    for (int i = 0; i < 8; ++i) {
        const int c = i * 256 + tid;
        const uint4 v = Wt4[c];
        const int byte = (c * 16) ^ (((c >> 4) & 7) << 4);
        *(uint4*)(wlds + byte) = v;
    }

    const int wv = tid >> 6;
    const int l  = tid & 63;
    const int lr = l & 15;
    const int g  = l >> 4;
    const int row0 = blockIdx.x * 64 + wv * 16;

    int arow = row0 + lr;
    if (arow >= NODES) arow = 0;
    const unsigned short* Ar = A + (size_t)arow * DF + g * 8;
    bf16x8 af[4];
    #pragma unroll
    for (int t = 0; t < 4; ++t) af[t] = *(const bf16x8*)(Ar + t * 32);

    float bv[8];
    #pragma unroll
    for (int nt = 0; nt < 8; ++nt) bv[nt] = bias[nt * 16 + lr];

    f32x4 acc[8];
    #pragma unroll
    for (int nt = 0; nt < 8; ++nt) acc[nt] = (f32x4)(0.f);

    __syncthreads();

    #pragma unroll
    for (int t = 0; t < 4; ++t) {
        #pragma unroll
        for (int nt = 0; nt < 8; ++nt) {
            const int byte = ((nt * 16 + lr) * 256 + ((((t * 4 + g) * 16) ^ ((l & 7) << 4))));
            const bf16x8 bf = *(const bf16x8*)(wlds + byte);
            acc[nt] = __builtin_amdgcn_mfma_f32_16x16x32_bf16(af[t], bf, acc[nt], 0, 0, 0);
        }
    }

    if constexpr (OUT_BF16) {
        unsigned char* my = epi + wv * 4096;
        #pragma unroll
        for (int nt = 0; nt < 8; ++nt) {
            #pragma unroll
            for (int r = 0; r < 4; ++r) {
                float v = acc[nt][r] + bv[nt];
                if (RELU) v = fmaxf(v, 0.f);
                const int R = g * 4 + r;
                const int byte = (R * 256 + (nt * 16 + lr) * 2) ^ ((R & 7) << 4);
                *(unsigned short*)(my + byte) = f2bf(v);
            }
        }
        __syncthreads();
        unsigned short* outh = (unsigned short*)outp;
        #pragma unroll
        for (int p = 0; p < 4; ++p) {
            const int R = p * 4 + g;
            const uint4 v = *(const uint4*)(my + ((R * 256 + lr * 16) ^ ((R & 7) << 4)));
            const int gr = row0 + R;
            if (gr < NODES) *(uint4*)(outh + (size_t)gr * DF + lr * 8) = v;
        }
    } else {
        float* outf = (float*)outp;
        #pragma unroll
        for (int nt = 0; nt < 8; ++nt) {
            #pragma unroll
            for (int r = 0; r < 4; ++r) {
                const int gr = row0 + g * 4 + r;
                float v = acc[nt][r] + bv[nt];
                if (RELU) v = fmaxf(v, 0.f);
                if (gr < NODES) outf[(size_t)gr * DF + nt * 16 + lr] = v;
            }
        }
    }
}

extern "C" void kernel_launch(void* const* d_in, const int* in_sizes, int n_in,
                              void* d_out, int out_size, void* d_ws, size_t ws_size,
                              hipStream_t stream) {
    const float* x  = (const float*)d_in[0];
    const int*   ei = (const int*)d_in[1];
    const float* W1 = (const float*)d_in[2];
    const float* b1 = (const float*)d_in[3];
    const float* W2 = (const float*)d_in[4];
    const float* b2 = (const float*)d_in[5];
    float* out = (float*)d_out;

    const int* src = ei;
    const int* dst = ei + EDGES;

    unsigned short* xb   = (unsigned short*)d_ws;
    unsigned short* abuf = xb + (size_t)NODES * DF;
    unsigned short* hb   = abuf + (size_t)NODES * DF;
    unsigned short* Wt1  = hb + (size_t)NODES * DF;
    unsigned short* Wt2  = Wt1 + 16384;
    int* iw = (int*)(Wt2 + 16384);
    int* deg        = iw;
    int* excl       = deg + NODES;
    int* offs       = excl + NODES;
    int* cursor     = offs + NODES + 1;
    int* bsums      = cursor + NODES;
    int* sorted_src = bsums + NBLK + 1;

    // ---- CSR build
    hipMemsetAsync(deg, 0, NODES * sizeof(int), stream);
    hist_kernel<<<(EDGES + 255) / 256, 256, 0, stream>>>(dst, deg);
    scan_blocks<<<NBLK, SCAN_B, 0, stream>>>(deg, excl, bsums);
    scan_top<<<1, 512, 0, stream>>>(bsums);
    scan_add<<<NBLK, SCAN_B, 0, stream>>>(excl, bsums, offs, cursor);
    fill_kernel<<<(EDGES + 255) / 256, 256, 0, stream>>>(src, dst, cursor, sorted_src);

    // ---- precompute bf16 views
    conv_bf16<<<2048, 256, 0, stream>>>((const float4*)x, (uint4*)xb, NODES * DF / 8);
    prep_w<<<128, 256, 0, stream>>>(W1, W2, Wt1, Wt2);

    const int gblocks = (NODES * 16 + 255) / 256;   // 6250
    const int mblocks = (NODES + 63) / 64;          // 1563

    // ---- layer 1
    gather_bf16<<<gblocks, 256, 0, stream>>>((const uint4*)xb, offs, sorted_src, (uint4*)abuf);
    mlp_mfma<1, 1><<<mblocks, 256, 0, stream>>>(abuf, (const uint4*)Wt1, b1, hb);

    // ---- layer 2
    gather_bf16<<<gblocks, 256, 0, stream>>>((const uint4*)hb, offs, sorted_src, (uint4*)abuf);
    mlp_mfma<0, 0><<<mblocks, 256, 0, stream>>>(abuf, (const uint4*)Wt2, b2, out);
}

// Round 7
// 178.191 us; speedup vs baseline: 4.4537x; 1.0036x over previous
//
#include <hip/hip_runtime.h>

#define NODES 100000
#define EDGES 640000
#define DF 128
#define SCAN_B 256
#define NBLK ((NODES + SCAN_B - 1) / SCAN_B)   // 391

typedef short bf16x8 __attribute__((ext_vector_type(8)));
typedef float f32x4 __attribute__((ext_vector_type(4)));

__device__ __forceinline__ unsigned short f2bf(float f) {
    unsigned u = __builtin_bit_cast(unsigned, f);
    u += 0x7FFFu + ((u >> 16) & 1u);          // round-to-nearest-even
    return (unsigned short)(u >> 16);
}
__device__ __forceinline__ float bflo(unsigned w) { return __builtin_bit_cast(float, w << 16); }
__device__ __forceinline__ float bfhi(unsigned w) { return __builtin_bit_cast(float, w & 0xFFFF0000u); }

// ---------------------------------------------------------------- zero deg (replaces pathological rocclr fill: 40us -> ~2us)
__global__ void zero_deg(uint4* __restrict__ p) {
    const int i = blockIdx.x * blockDim.x + threadIdx.x;
    if (i < NODES / 4) p[i] = make_uint4(0u, 0u, 0u, 0u);
}

// ---------------------------------------------------------------- CSR build
__global__ void hist_kernel(const int* __restrict__ dstIdx, int* __restrict__ deg) {
    int e = blockIdx.x * blockDim.x + threadIdx.x;
    if (e < EDGES) atomicAdd(&deg[dstIdx[e]], 1);
}

__global__ __launch_bounds__(SCAN_B) void scan_blocks(const int* __restrict__ deg,
                                                      int* __restrict__ excl,
                                                      int* __restrict__ bsums) {
    __shared__ int tmp[SCAN_B];
    const int i = blockIdx.x * SCAN_B + threadIdx.x;
    const int v = (i < NODES) ? deg[i] : 0;
    tmp[threadIdx.x] = v;
    __syncthreads();
    for (int off = 1; off < SCAN_B; off <<= 1) {
        int t = 0;
        if (threadIdx.x >= off) t = tmp[threadIdx.x - off];
        __syncthreads();
        if (threadIdx.x >= off) tmp[threadIdx.x] += t;
        __syncthreads();
    }
    if (i < NODES) excl[i] = tmp[threadIdx.x] - v;
    if (threadIdx.x == SCAN_B - 1) bsums[blockIdx.x] = tmp[SCAN_B - 1];
}

__global__ __launch_bounds__(512) void scan_top(int* __restrict__ bsums) {
    __shared__ int tmp[512];
    const int i = threadIdx.x;
    const int v = (i < NBLK) ? bsums[i] : 0;
    tmp[i] = v;
    __syncthreads();
    for (int off = 1; off < 512; off <<= 1) {
        int t = 0;
        if (i >= off) t = tmp[i - off];
        __syncthreads();
        if (i >= off) tmp[i] += t;
        __syncthreads();
    }
    if (i < NBLK) bsums[i] = tmp[i] - v;
}

__global__ __launch_bounds__(SCAN_B) void scan_add(const int* __restrict__ excl,
                                                   const int* __restrict__ bsums,
                                                   int* __restrict__ offs,
                                                   int* __restrict__ cursor) {
    const int i = blockIdx.x * SCAN_B + threadIdx.x;
    if (i < NODES) {
        const int o = excl[i] + bsums[blockIdx.x];
        offs[i] = o;
        cursor[i] = o;
    }
    if (i == 0) offs[NODES] = EDGES;
}

__global__ void fill_kernel(const int* __restrict__ srcIdx,
                            const int* __restrict__ dstIdx,
                            int* __restrict__ cursor,
                            int* __restrict__ sorted_src) {
    int e = blockIdx.x * blockDim.x + threadIdx.x;
    if (e < EDGES) {
        const int d = dstIdx[e];
        const int pos = atomicAdd(&cursor[d], 1);
        sorted_src[pos] = srcIdx[e];
    }
}

// ---------------------------------------------------------------- f32 -> bf16 convert (8 elems/thread)
__global__ void conv_bf16(const float4* __restrict__ in, uint4* __restrict__ out, int nchunk) {
    int i = blockIdx.x * blockDim.x + threadIdx.x;
    const int stride = gridDim.x * blockDim.x;
    for (; i < nchunk; i += stride) {
        const float4 a = in[i * 2], b = in[i * 2 + 1];
        uint4 o;
        o.x = (unsigned)f2bf(a.x) | ((unsigned)f2bf(a.y) << 16);
        o.y = (unsigned)f2bf(a.z) | ((unsigned)f2bf(a.w) << 16);
        o.z = (unsigned)f2bf(b.x) | ((unsigned)f2bf(b.y) << 16);
        o.w = (unsigned)f2bf(b.z) | ((unsigned)f2bf(b.w) << 16);
        out[i] = o;
    }
}

// ---------------------------------------------------------------- W [k][n] f32 -> Wt [n][k] bf16 (both layers)
__global__ void prep_w(const float* __restrict__ W1, const float* __restrict__ W2,
                       unsigned short* __restrict__ Wt1, unsigned short* __restrict__ Wt2) {
    const int idx = blockIdx.x * blockDim.x + threadIdx.x;   // 0..32767
    const float* src = (idx < 16384) ? W1 : W2;
    unsigned short* dst = (idx < 16384) ? Wt1 : Wt2;
    const int r = idx & 16383;
    const int n = r & 127, k = r >> 7;
    dst[n * 128 + k] = f2bf(src[k * 128 + n]);
}

// ---------------------------------------------------------------- gather: A[i] = x[i] + sum_{j in N(i)} x[j]
// 16 lanes/node, 16B/lane; 4-way edge unroll for memory-level parallelism
__global__ __launch_bounds__(256) void gather_bf16(const uint4* __restrict__ xb,
                                                   const int* __restrict__ offs,
                                                   const int* __restrict__ ssrc,
                                                   uint4* __restrict__ ab) {
    const int gid = blockIdx.x * 256 + threadIdx.x;
    const int node = gid >> 4;
    const int lane = gid & 15;
    if (node >= NODES) return;

    float a[8];
    {
        const uint4 u = xb[(size_t)node * 16 + lane];
        a[0] = bflo(u.x); a[1] = bfhi(u.x);
        a[2] = bflo(u.y); a[3] = bfhi(u.y);
        a[4] = bflo(u.z); a[5] = bfhi(u.z);
        a[6] = bflo(u.w); a[7] = bfhi(u.w);
    }
    const int beg = offs[node];
    const int end = offs[node + 1];
    int j = beg;
    for (; j + 4 <= end; j += 4) {
        const int s0 = ssrc[j + 0];
        const int s1 = ssrc[j + 1];
        const int s2 = ssrc[j + 2];
        const int s3 = ssrc[j + 3];
        const uint4 v0 = xb[(size_t)s0 * 16 + lane];
        const uint4 v1 = xb[(size_t)s1 * 16 + lane];
        const uint4 v2 = xb[(size_t)s2 * 16 + lane];
        const uint4 v3 = xb[(size_t)s3 * 16 + lane];
        a[0] += bflo(v0.x); a[1] += bfhi(v0.x); a[2] += bflo(v0.y); a[3] += bfhi(v0.y);
        a[4] += bflo(v0.z); a[5] += bfhi(v0.z); a[6] += bflo(v0.w); a[7] += bfhi(v0.w);
        a[0] += bflo(v1.x); a[1] += bfhi(v1.x); a[2] += bflo(v1.y); a[3] += bfhi(v1.y);
        a[4] += bflo(v1.z); a[5] += bfhi(v1.z); a[6] += bflo(v1.w); a[7] += bfhi(v1.w);
        a[0] += bflo(v2.x); a[1] += bfhi(v2.x); a[2] += bflo(v2.y); a[3] += bfhi(v2.y);
        a[4] += bflo(v2.z); a[5] += bfhi(v2.z); a[6] += bflo(v2.w); a[7] += bfhi(v2.w);
        a[0] += bflo(v3.x); a[1] += bfhi(v3.x); a[2] += bflo(v3.y); a[3] += bfhi(v3.y);
        a[4] += bflo(v3.z); a[5] += bfhi(v3.z); a[6] += bflo(v3.w); a[7] += bfhi(v3.w);
    }
    for (; j < end; ++j) {
        const uint4 v = xb[(size_t)ssrc[j] * 16 + lane];
        a[0] += bflo(v.x); a[1] += bfhi(v.x); a[2] += bflo(v.y); a[3] += bfhi(v.y);
        a[4] += bflo(v.z); a[5] += bfhi(v.z); a[6] += bflo(v.w); a[7] += bfhi(v.w);
    }
    uint4 o;
    o.x = (unsigned)f2bf(a[0]) | ((unsigned)f2bf(a[1]) << 16);
    o.y = (unsigned)f2bf(a[2]) | ((unsigned)f2bf(a[3]) << 16);
    o.z = (unsigned)f2bf(a[4]) | ((unsigned)f2bf(a[5]) << 16);
    o.w = (unsigned)f2bf(a[6]) | ((unsigned)f2bf(a[7]) << 16);
    ab[(size_t)node * 16 + lane] = o;
}

// ---------------------------------------------------------------- MFMA MLP: out = A @ Wt^T + b
template <int RELU, int OUT_BF16>
__global__ __launch_bounds__(256) void mlp_mfma(const unsigned short* __restrict__ A,
                                                const uint4* __restrict__ Wt4,
                                                const float* __restrict__ bias,
                                                void* __restrict__ outp) {
    __shared__ __align__(16) unsigned char wlds[32768];
    __shared__ __align__(16) unsigned char epi[OUT_BF16 ? 16384 : 16];

    const int tid = threadIdx.x;
    #pragma unroll
    for (int i = 0; i < 8; ++i) {
        const int c = i * 256 + tid;
        const uint4 v = Wt4[c];
        const int byte = (c * 16) ^ (((c >> 4) & 7) << 4);
        *(uint4*)(wlds + byte) = v;
    }

    const int wv = tid >> 6;
    const int l  = tid & 63;
    const int lr = l & 15;
    const int g  = l >> 4;
    const int row0 = blockIdx.x * 64 + wv * 16;

    int arow = row0 + lr;
    if (arow >= NODES) arow = 0;
    const unsigned short* Ar = A + (size_t)arow * DF + g * 8;
    bf16x8 af[4];
    #pragma unroll
    for (int t = 0; t < 4; ++t) af[t] = *(const bf16x8*)(Ar + t * 32);

    float bv[8];
    #pragma unroll
    for (int nt = 0; nt < 8; ++nt) bv[nt] = bias[nt * 16 + lr];

    f32x4 acc[8];
    #pragma unroll
    for (int nt = 0; nt < 8; ++nt) acc[nt] = (f32x4)(0.f);

    __syncthreads();

    #pragma unroll
    for (int t = 0; t < 4; ++t) {
        #pragma unroll
        for (int nt = 0; nt < 8; ++nt) {
            const int byte = ((nt * 16 + lr) * 256 + ((((t * 4 + g) * 16) ^ ((l & 7) << 4))));
            const bf16x8 bf = *(const bf16x8*)(wlds + byte);
            acc[nt] = __builtin_amdgcn_mfma_f32_16x16x32_bf16(af[t], bf, acc[nt], 0, 0, 0);
        }
    }

    if constexpr (OUT_BF16) {
        unsigned char* my = epi + wv * 4096;
        #pragma unroll
        for (int nt = 0; nt < 8; ++nt) {
            #pragma unroll
            for (int r = 0; r < 4; ++r) {
                float v = acc[nt][r] + bv[nt];
                if (RELU) v = fmaxf(v, 0.f);
                const int R = g * 4 + r;
                const int byte = (R * 256 + (nt * 16 + lr) * 2) ^ ((R & 7) << 4);
                *(unsigned short*)(my + byte) = f2bf(v);
            }
        }
        __syncthreads();
        unsigned short* outh = (unsigned short*)outp;
        #pragma unroll
        for (int p = 0; p < 4; ++p) {
            const int R = p * 4 + g;
            const uint4 v = *(const uint4*)(my + ((R * 256 + lr * 16) ^ ((R & 7) << 4)));
            const int gr = row0 + R;
            if (gr < NODES) *(uint4*)(outh + (size_t)gr * DF + lr * 8) = v;
        }
    } else {
        float* outf = (float*)outp;
        #pragma unroll
        for (int nt = 0; nt < 8; ++nt) {
            #pragma unroll
            for (int r = 0; r < 4; ++r) {
                const int gr = row0 + g * 4 + r;
                float v = acc[nt][r] + bv[nt];
                if (RELU) v = fmaxf(v, 0.f);
                if (gr < NODES) outf[(size_t)gr * DF + nt * 16 + lr] = v;
            }
        }
    }
}

extern "C" void kernel_launch(void* const* d_in, const int* in_sizes, int n_in,
                              void* d_out, int out_size, void* d_ws, size_t ws_size,
                              hipStream_t stream) {
    const float* x  = (const float*)d_in[0];
    const int*   ei = (const int*)d_in[1];
    const float* W1 = (const float*)d_in[2];
    const float* b1 = (const float*)d_in[3];
    const float* W2 = (const float*)d_in[4];
    const float* b2 = (const float*)d_in[5];
    float* out = (float*)d_out;

    const int* src = ei;
    const int* dst = ei + EDGES;

    unsigned short* xb   = (unsigned short*)d_ws;
    unsigned short* abuf = xb + (size_t)NODES * DF;
    unsigned short* hb   = abuf + (size_t)NODES * DF;
    unsigned short* Wt1  = hb + (size_t)NODES * DF;
    unsigned short* Wt2  = Wt1 + 16384;
    int* iw = (int*)(Wt2 + 16384);
    int* deg        = iw;
    int* excl       = deg + NODES;
    int* offs       = excl + NODES;
    int* cursor     = offs + NODES + 1;
    int* bsums      = cursor + NODES;
    int* sorted_src = bsums + NBLK + 1;

    // ---- CSR build (custom zero kernel: rocclr fill was 40us for 400KB)
    zero_deg<<<(NODES / 4 + 255) / 256, 256, 0, stream>>>((uint4*)deg);
    hist_kernel<<<(EDGES + 255) / 256, 256, 0, stream>>>(dst, deg);
    scan_blocks<<<NBLK, SCAN_B, 0, stream>>>(deg, excl, bsums);
    scan_top<<<1, 512, 0, stream>>>(bsums);
    scan_add<<<NBLK, SCAN_B, 0, stream>>>(excl, bsums, offs, cursor);
    fill_kernel<<<(EDGES + 255) / 256, 256, 0, stream>>>(src, dst, cursor, sorted_src);

    // ---- precompute bf16 views
    conv_bf16<<<2048, 256, 0, stream>>>((const float4*)x, (uint4*)xb, NODES * DF / 8);
    prep_w<<<128, 256, 0, stream>>>(W1, W2, Wt1, Wt2);

    const int gblocks = (NODES * 16 + 255) / 256;   // 6250
    const int mblocks = (NODES + 63) / 64;          // 1563

    // ---- layer 1
    gather_bf16<<<gblocks, 256, 0, stream>>>((const uint4*)xb, offs, sorted_src, (uint4*)abuf);
    mlp_mfma<1, 1><<<mblocks, 256, 0, stream>>>(abuf, (const uint4*)Wt1, b1, hb);

    // ---- layer 2
    gather_bf16<<<gblocks, 256, 0, stream>>>((const uint4*)hb, offs, sorted_src, (uint4*)abuf);
    mlp_mfma<0, 0><<<mblocks, 256, 0, stream>>>(abuf, (const uint4*)Wt2, b2, out);
}